// Round 2
// 132.007 us; speedup vs baseline: 1.0725x; 1.0725x over previous
//
#include <hip/hip_runtime.h>
#include <hip/hip_bf16.h>

// ---------------------------------------------------------------------------
// SelfAttention_Conv2D: B=4, H=W=64 (n=4096), C=128.
// Round 12 (= R11 resubmit; R11 failed at container level, no kernel verdict):
// MX-scaled fp8 MFMA in attn (unit scales = numerically identical).
//   - QK^T: mfma_scale_f32_16x16x128_f8f6f4, K=128 = full channel dim in ONE
//     instruction (was 4x chained 16x16x32). C/D layout identical -> exp/pack
//     section byte-identical to R10.
//   - PV:   mfma_scale_f32_32x32x64_f8f6f4, K=64 = full key tile in ONE
//     instruction per 32-ch tile; merges both q-subs (A rows = 32 queries).
//   - fp8 MX rate is ~4.65 PF vs ~2.08 PF non-scaled: MFMA pipe 16.6->7.4us.
//   - Hardening vs R11: scale operand = 0x7F7F7F7F (every byte = e8m0 unit)
//     so any opsel byte-select convention still yields scale 1.0.
// Residue ledger: 2x 43us fillBuffer = harness ws re-poison (~86us fixed);
// attn (~42us) is the only real target. Ledger: (R5) never cap regs below
// demand; (R6) regs cap occupancy not LDS; (R7) never drop cross-iter
// prefetch; (R8/R9) fp8 QK+PV numerically free; (R10) packed P-strip writes.
// ---------------------------------------------------------------------------

typedef __hip_bfloat16 bf16;
typedef unsigned char u8;
typedef unsigned int  u32;
typedef unsigned long long u64;
typedef float  floatx4  __attribute__((ext_vector_type(4)));
typedef float  floatx16 __attribute__((ext_vector_type(16)));
typedef short  shortx8 __attribute__((ext_vector_type(8)));
typedef short  shortx4 __attribute__((ext_vector_type(4)));
typedef u32    uintx4  __attribute__((ext_vector_type(4)));
typedef int    intx8   __attribute__((ext_vector_type(8)));

#define CDIM 128
#define NROW 16384            // B*n
#define NPB  4096             // n per batch
#define LDW  136              // LDS stride (el) for 128-wide bf16 rows
#define LDG8 144              // LDS stride (BYTES) gs8: 128-wide fp8 rows
#define LDV8 80               // LDS stride (BYTES) vs8/ps8: 64-wide fp8 rows
#define QTILE 128             // queries per attn WG
#define NKT  64               // total 64-key tiles (4096 keys)
#define OSCALE 0.125f         // Opart fp8 scale (dequant folded into 8/L)
#define UNIT_SCALE 0x7F7F7F7F // e8m0 127 in every byte -> 1.0 for any opsel

// unit block-scales, fp8 e4m3 A/B formats (cbsz=0, blgp=0)
#define MFMA_QK(a, b, c) \
    __builtin_amdgcn_mfma_scale_f32_16x16x128_f8f6f4((a), (b), (c), 0, 0, \
        0, UNIT_SCALE, 0, UNIT_SCALE)
#define MFMA_PV(a, b, c) \
    __builtin_amdgcn_mfma_scale_f32_32x32x64_f8f6f4((a), (b), (c), 0, 0, \
        0, UNIT_SCALE, 0, UNIT_SCALE)

__device__ __forceinline__ short f2bf(float v) {
    union { __hip_bfloat16 h; short s; } u; u.h = __float2bfloat16(v); return u.s;
}
__device__ __forceinline__ float bf2f(short s) {
    union { short s2; __hip_bfloat16 h; } u; u.s2 = s; return __bfloat162float(u.h);
}
__device__ __forceinline__ u8 f2fp8(float v) {
    int p = __builtin_amdgcn_cvt_pk_fp8_f32(v, v, 0, false);
    return (u8)(p & 0xff);
}
__device__ __forceinline__ u32 f2fp8x4(float a, float b, float c, float d) {
    int w = __builtin_amdgcn_cvt_pk_fp8_f32(a, b, 0, false);
    w = __builtin_amdgcn_cvt_pk_fp8_f32(c, d, w, true);
    return (u32)w;
}
// 32-byte load (2x b128) -> v8i32 fragment; works for LDS and global pointers
__device__ __forceinline__ intx8 ld32(const u8* p) {
    uintx4 a = *(const uintx4*)p;
    uintx4 b = *(const uintx4*)(p + 16);
    intx8 r;
    r[0] = (int)a[0]; r[1] = (int)a[1]; r[2] = (int)a[2]; r[3] = (int)a[3];
    r[4] = (int)b[0]; r[5] = (int)b[1]; r[6] = (int)b[2]; r[7] = (int)b[3];
    return r;
}

// ---------------------------------------------------------------------------
// K1: one projection matrix per WG (unchanged from R9/R10, verified).
// ---------------------------------------------------------------------------
__global__ __launch_bounds__(256) void proj3_kernel(
    const float* __restrict__ x,
    const float* __restrict__ Wf, const float* __restrict__ bf_,
    const float* __restrict__ Wg, const float* __restrict__ bg_,
    const float* __restrict__ Wh, const float* __restrict__ bh_,
    u8* __restrict__ f8, u8* __restrict__ g8, u8* __restrict__ vT8)
{
    __shared__ bf16 wt[128 * LDW];   // wt[n][k] = W[k][n]; reused as vt bounce

    const int t    = threadIdx.x;
    const int wave = t >> 6, lane = t & 63;
    const int quad = lane >> 4, l16 = lane & 15;
    const int mtx    = blockIdx.x >> 8;
    const int rowblk = (blockIdx.x & 255) * 64;
    const int row    = rowblk + wave * 16 + l16;

    const float* Ws[3] = {Wf, Wg, Wh};
    const float* Bs[3] = {bf_, bg_, bh_};
    const float* W    = Ws[mtx];
    const float* bias = Bs[mtx];

    for (int i = t; i < 128 * 32; i += 256) {
        int k = i >> 5, n0 = (i & 31) * 4;
        floatx4 wv = *(const floatx4*)(W + k * CDIM + n0);
#pragma unroll
        for (int j = 0; j < 4; ++j)
            *(short*)&wt[(n0 + j) * LDW + k] = f2bf(wv[j]);
    }

    shortx8 afr[4];
    {
        const float* xp = x + (size_t)row * CDIM + quad * 8;
#pragma unroll
        for (int kc = 0; kc < 4; ++kc) {
            floatx4 u = *(const floatx4*)(xp + kc * 32);
            floatx4 w = *(const floatx4*)(xp + kc * 32 + 4);
            shortx8 a;
            a[0]=f2bf(u[0]); a[1]=f2bf(u[1]); a[2]=f2bf(u[2]); a[3]=f2bf(u[3]);
            a[4]=f2bf(w[0]); a[5]=f2bf(w[1]); a[6]=f2bf(w[2]); a[7]=f2bf(w[3]);
            afr[kc] = a;
        }
    }
    __syncthreads();

    floatx4 acc[8];
#pragma unroll
    for (int nt = 0; nt < 8; ++nt) acc[nt] = (floatx4){0.f, 0.f, 0.f, 0.f};
#pragma unroll
    for (int nt = 0; nt < 8; ++nt) {
        const bf16* wrow = &wt[(nt * 16 + l16) * LDW + quad * 8];
#pragma unroll
        for (int kc = 0; kc < 4; ++kc) {
            shortx8 b = *(const shortx8*)(wrow + kc * 32);
            acc[nt] = __builtin_amdgcn_mfma_f32_16x16x32_bf16(afr[kc], b, acc[nt], 0, 0, 0);
        }
    }

    if (mtx < 2) {
        u8* dst = (mtx == 0) ? f8 : g8;
#pragma unroll
        for (int nt = 0; nt < 8; ++nt) {
            int col = nt * 16 + l16;
            float bv_ = bias[col];
#pragma unroll
            for (int r = 0; r < 4; ++r) {
                int orow = rowblk + wave * 16 + quad * 4 + r;
                dst[(size_t)orow * CDIM + col] = f2fp8(acc[nt][r] + bv_);
            }
        }
    } else {
        // vT fp8 via LDS bounce: tile [ch][n] 128x64 B, coalesced 16B stores
        __syncthreads();
        u8* vt8 = (u8*)wt;
        const int nloc0 = wave * 16 + quad * 4;
#pragma unroll
        for (int nt = 0; nt < 8; ++nt) {
            int ch = nt * 16 + l16;
            float bv_ = bias[ch];
            *(u32*)&vt8[ch * LDV8 + nloc0] =
                f2fp8x4(acc[nt][0] + bv_, acc[nt][1] + bv_,
                        acc[nt][2] + bv_, acc[nt][3] + bv_);
        }
        __syncthreads();
        const int ch  = t >> 1;
        const int off = (t & 1) * 32;
        const int batch = rowblk >> 12;
        const int n0 = (rowblk & 4095) + off;
        u8* dst = &vT8[((size_t)batch * CDIM + ch) * NPB + n0];
        const u8* src = &vt8[ch * LDV8 + off];
#pragma unroll
        for (int j = 0; j < 2; ++j)
            *(uintx4*)(dst + j * 16) = *(const uintx4*)(src + j * 16);
    }
}

// ---------------------------------------------------------------------------
// K2: flash attention, transposed-S, MX-scaled fp8 MFMA (unit scales).
// blockIdx.x = qg, .y = split; K-tile range [kt0,kt1).
// ---------------------------------------------------------------------------
__global__ __launch_bounds__(256, 3) void attn_kernel(
    const u8* __restrict__ f8, const u8* __restrict__ g8,
    const u8* __restrict__ vT8,
    u8* __restrict__ Opart8, float* __restrict__ lbuf, int nsplit)
{
    __shared__ u8 gs8[64 * LDG8];        // g tile [key][ch]  fp8  9216 B
    __shared__ u8 vs8[128 * LDV8];       // v tile [ch][key]  fp8 10240 B
    __shared__ u8 ps8[4 * 32 * LDV8];    // P strips [q][key] fp8 10240 B

    const int t    = threadIdx.x;
    const int wave = t >> 6, lane = t & 63;
    const int quad = lane >> 4, l16 = lane & 15;
    const int c31  = lane & 31, hf = lane >> 5;
    const int qg    = blockIdx.x;
    const int split = blockIdx.y;
    const int b  = qg >> 5;
    const int qt = qg & 31;
    const int qbase = b * NPB + qt * QTILE + wave * 32;

    const int kt0 = (split * NKT) / nsplit;
    const int kt1 = ((split + 1) * NKT) / nsplit;

    // Q frags (B-operand, K=128): lane holds q=l16 row, channel block quad*32..+31
    intx8 qf8[2];
#pragma unroll
    for (int sub = 0; sub < 2; ++sub)
        qf8[sub] = ld32(f8 + (size_t)(qbase + sub * 16 + l16) * CDIM + quad * 32);

    floatx16 o[4];
#pragma unroll
    for (int ct = 0; ct < 4; ++ct)
#pragma unroll
        for (int i = 0; i < 16; ++i) o[ct][i] = 0.f;
    float lacc[2] = {0.f, 0.f};          // per-lane l partial (q = l16 fixed)

    const u8* gptr = g8 + (size_t)b * NPB * CDIM;
    const u8* vptr = vT8 + (size_t)b * CDIM * NPB;

    const int gk = t >> 2, go = (t & 3) * 32;
    const int vch = t >> 1, vo = (t & 1) * 32;

    shortx8 gx[2], vx[2];
#pragma unroll
    for (int i = 0; i < 2; ++i) {
        gx[i] = *(const shortx8*)&gptr[(size_t)(kt0 * 64 + gk) * CDIM + go + i * 16];
        vx[i] = *(const shortx8*)&vptr[(size_t)vch * NPB + kt0 * 64 + vo + i * 16];
    }

    for (int kt = kt0; kt < kt1; ++kt) {
        __syncthreads();                  // prev tile consumers done
#pragma unroll
        for (int i = 0; i < 2; ++i) {
            *(shortx8*)&gs8[gk * LDG8 + go + i * 16] = gx[i];
            *(shortx8*)&vs8[vch * LDV8 + vo + i * 16] = vx[i];
        }
        if (kt + 1 < kt1) {               // prefetch next tile (hides latency)
            const int ktn = kt + 1;
#pragma unroll
            for (int i = 0; i < 2; ++i) {
                gx[i] = *(const shortx8*)&gptr[(size_t)(ktn * 64 + gk) * CDIM + go + i * 16];
                vx[i] = *(const shortx8*)&vptr[(size_t)vch * NPB + ktn * 64 + vo + i * 16];
            }
        }
        __syncthreads();                  // tile visible

        // ---- S^T = mfma_scale K=128 (A=g row=key, B=q col=query):
        //      one instruction per (sub, nt); C/D layout same as 16x16x32.
        floatx4 s[2][4];
#pragma unroll
        for (int nt = 0; nt < 4; ++nt) {
            s[0][nt] = (floatx4){0.f, 0.f, 0.f, 0.f};
            s[1][nt] = (floatx4){0.f, 0.f, 0.f, 0.f};
        }
#pragma unroll
        for (int nt = 0; nt < 4; ++nt) {
            intx8 gf = ld32(&gs8[(nt * 16 + l16) * LDG8 + quad * 32]);
            s[0][nt] = MFMA_QK(gf, qf8[0], s[0][nt]);
            s[1][nt] = MFMA_QK(gf, qf8[1], s[1][nt]);
        }

        // ---- exp -> P strip [q][key] via packed b32 writes (4 keys/lane);
        //      per-lane l accumulate (q = l16 fixed; no per-iter shuffles)
#pragma unroll
        for (int sub = 0; sub < 2; ++sub) {
            u8* pw = &ps8[(wave * 32 + sub * 16 + l16) * LDV8 + quad * 4];
#pragma unroll
            for (int nt = 0; nt < 4; ++nt) {
                float p0 = __expf(s[sub][nt][0]);
                float p1 = __expf(s[sub][nt][1]);
                float p2 = __expf(s[sub][nt][2]);
                float p3 = __expf(s[sub][nt][3]);
                lacc[sub] += (p0 + p1) + (p2 + p3);
                *(u32*)&pw[nt * 16] = f2fp8x4(p0, p1, p2, p3);
            }
        }

        // ---- P back as 32x32x64 A-frag: lane = q-row c31, key block hf*32..+31
        //      (same-wave strip, rows wave*32..+31 all written by this wave)
        intx8 pa8 = ld32(&ps8[(wave * 32 + c31) * LDV8 + hf * 32]);

        // ---- O += P @ V: one mfma_scale 32x32x64 per 32-ch tile (merges subs)
#pragma unroll
        for (int ct = 0; ct < 4; ++ct) {
            intx8 vf = ld32(&vs8[(ct * 32 + c31) * LDV8 + hf * 32]);
            o[ct] = MFMA_PV(pa8, vf, o[ct]);
        }
    }

    // ---- epilogue: Opart fp8 (scale 1/8), 32x32 C/D layout:
    //      col = ct*32 + (lane&31), row = (i&3) + 8*(i>>2) + 4*(lane>>5)
    const size_t pbase = ((size_t)qg * nsplit + split) * QTILE * CDIM;
#pragma unroll
    for (int ct = 0; ct < 4; ++ct) {
        int col = ct * 32 + c31;
#pragma unroll
        for (int i = 0; i < 16; ++i) {
            int rl = wave * 32 + (i & 3) + 8 * (i >> 2) + 4 * hf;
            Opart8[pbase + (size_t)rl * CDIM + col] = f2fp8(o[ct][i] * OSCALE);
        }
    }
    float* lb = lbuf + ((size_t)qg * nsplit + split) * QTILE;
#pragma unroll
    for (int sub = 0; sub < 2; ++sub) {
        float v = lacc[sub];
        v += __shfl_xor(v, 16);
        v += __shfl_xor(v, 32);
        if (quad == 0) lb[wave * 32 + sub * 16 + l16] = v;
    }
}

// ---------------------------------------------------------------------------
// K3: fused combine + output proj. Opart fp8: dequant x8 folded into inv.
// ---------------------------------------------------------------------------
__global__ __launch_bounds__(256) void out_kernel(
    const u8* __restrict__ Opart8, const float* __restrict__ lbuf,
    const float* __restrict__ Wv, const float* __restrict__ bv,
    const float* __restrict__ x, const float* __restrict__ gamma,
    float* __restrict__ out, int nsplit)
{
    __shared__ bf16 wt[128 * LDW];

    const int t    = threadIdx.x;
    const int wave = t >> 6, lane = t & 63;
    const int quad = lane >> 4, l16 = lane & 15;
    const int rowblk = blockIdx.x * 64;
    const int row    = rowblk + wave * 16 + l16;

    const float gm = gamma[0];
    for (int i = t; i < 128 * 32; i += 256) {
        int k = i >> 5, n0 = (i & 31) * 4;
        floatx4 wv4 = *(const floatx4*)(Wv + k * CDIM + n0);
#pragma unroll
        for (int j = 0; j < 4; ++j)
            *(short*)&wt[(n0 + j) * LDW + k] = f2bf(wv4[j] * gm);
    }

    const int qg = row >> 7, rl = row & 127;   // QTILE = 128
    float L = 0.f;
    for (int s = 0; s < nsplit; ++s)
        L += lbuf[((size_t)qg * nsplit + s) * QTILE + rl];
    const float inv = 8.0f / L;                // 8 = 1/OSCALE dequant

    shortx8 afr[4];
#pragma unroll
    for (int kc = 0; kc < 4; ++kc) {
        float a8[8] = {0,0,0,0,0,0,0,0};
        for (int s = 0; s < nsplit; ++s) {
            const u8* p = &Opart8[(((size_t)qg * nsplit + s) * QTILE + rl) * CDIM + quad * 8 + kc * 32];
            u32 lo = *(const u32*)p;
            u32 hi = *(const u32*)(p + 4);
            a8[0] += __builtin_amdgcn_cvt_f32_fp8(lo, 0);
            a8[1] += __builtin_amdgcn_cvt_f32_fp8(lo, 1);
            a8[2] += __builtin_amdgcn_cvt_f32_fp8(lo, 2);
            a8[3] += __builtin_amdgcn_cvt_f32_fp8(lo, 3);
            a8[4] += __builtin_amdgcn_cvt_f32_fp8(hi, 0);
            a8[5] += __builtin_amdgcn_cvt_f32_fp8(hi, 1);
            a8[6] += __builtin_amdgcn_cvt_f32_fp8(hi, 2);
            a8[7] += __builtin_amdgcn_cvt_f32_fp8(hi, 3);
        }
        shortx8 a;
#pragma unroll
        for (int j = 0; j < 8; ++j) a[j] = f2bf(a8[j] * inv);
        afr[kc] = a;
    }
    __syncthreads();

    floatx4 acc[8];
#pragma unroll
    for (int nt = 0; nt < 8; ++nt) acc[nt] = (floatx4){0.f, 0.f, 0.f, 0.f};
#pragma unroll
    for (int nt = 0; nt < 8; ++nt) {
        const bf16* wrow = &wt[(nt * 16 + l16) * LDW + quad * 8];
#pragma unroll
        for (int kc = 0; kc < 4; ++kc) {
            shortx8 b = *(const shortx8*)(wrow + kc * 32);
            acc[nt] = __builtin_amdgcn_mfma_f32_16x16x32_bf16(afr[kc], b, acc[nt], 0, 0, 0);
        }
    }

#pragma unroll
    for (int nt = 0; nt < 8; ++nt) {
        int col = nt * 16 + l16;
        float bias = bv[col];
#pragma unroll
        for (int r = 0; r < 4; ++r) {
            int orow = rowblk + wave * 16 + quad * 4 + r;
            size_t idx = (size_t)orow * CDIM + col;
            out[idx] = acc[nt][r] + bias + x[idx];
        }
    }
}

// ---------------------------------------------------------------------------
extern "C" void kernel_launch(void* const* d_in, const int* in_sizes, int n_in,
                              void* d_out, int out_size, void* d_ws, size_t ws_size,
                              hipStream_t stream)
{
    const float* x   = (const float*)d_in[0];
    const float* Wf  = (const float*)d_in[1];
    const float* bf_ = (const float*)d_in[2];
    const float* Wg  = (const float*)d_in[3];
    const float* bg_ = (const float*)d_in[4];
    const float* Wh  = (const float*)d_in[5];
    const float* bh_ = (const float*)d_in[6];
    const float* Wv  = (const float*)d_in[7];
    const float* bv  = (const float*)d_in[8];
    const float* gm  = (const float*)d_in[9];
    float* out = (float*)d_out;

    // nsplit=6 -> grid 768 WGs = 3 WG/CU. Fallback 4 if ws too small.
    const size_t need6 = (size_t)3 * NROW * CDIM                       // f8,g8,vT8
                       + (size_t)128 * 6 * QTILE * CDIM                // Opart fp8
                       + (size_t)128 * 6 * QTILE * 4;                  // lbuf
    const int nsplit = (ws_size >= need6) ? 6 : 4;

    u8*   f8    = (u8*)d_ws;
    u8*   g8    = f8 + (size_t)NROW * CDIM;
    u8*   vT8   = g8 + (size_t)NROW * CDIM;
    u8*   Opart8 = vT8 + (size_t)NROW * CDIM;
    float* lbuf = (float*)(Opart8 + (size_t)128 * nsplit * QTILE * CDIM);

    proj3_kernel<<<768, 256, 0, stream>>>(x, Wf, bf_, Wg, bg_, Wh, bh_, f8, g8, vT8);
    attn_kernel<<<dim3(128, nsplit), 256, 0, stream>>>(f8, g8, vT8, Opart8, lbuf, nsplit);
    out_kernel<<<256, 256, 0, stream>>>(Opart8, lbuf, Wv, bv, x, gm, out, nsplit);
}